// Round 11
// baseline (491.150 us; speedup 1.0000x reference)
//
#include <hip/hip_runtime.h>

// PinkNet: x(512,24,24,10,1) -T-> (B,1,T,Y,X) -conv1(dil 2,2)-> relu -> *mask
//          -conv2-> -T-> out.
// r32: tp-major slot renumbering -> compile-time kt-zero skip in conv2.
//      r30's skip failed on RUNTIME tp branches; r32 makes tp COMPILE-TIME:
//      slots sorted (typ, tp, ey, ex) [we own the numbering end-to-end].
//      Per-(typ,tp,ey) tables: rowb2[960] (exclusive base), tpbm[960]
//      (24-bit ex mask); run bounds via scalar popc. conv2: unrolled tp loop
//      -> straight-line 27.6-avg FMAs/slot (ot in [tp-2,tp+7]), weights stay
//      SGPR operands, depth-2 slot pipeline. conv1m epilogue & k_meta
//      renumbered to match. Reassociation only (absmax ~0.03 vs 0.299).
//      conv1m = r31 (3-product split). Others unchanged.
//
// ws ints @0: rowb2[960], tpbm[960]@960, basep[4]@4608, cellmeta[5760]@5120
// floats: mval[5760] @14336 ; FBASE=20480:
//   [FBASE..FBASE+4P)  part (conv2 out). conv1-only aliases (5.77M < 4P):
//     xbh @+0 (1572864 fl), xbl @+1572864, w1mh @+3145728 (1310720 fl),
//     w1ml @+4456448
//   [FBASE+4P..FBASE+5P) h1c[5760][512] fp32
//   [FBASE+5P..]         wz[224000]

#define NSLOT 5760
static constexpr int P     = 10 * 24 * 24 * 512;     // 2,949,120 = NSLOT*512
static constexpr int FBASE = 20480;
static constexpr int WZN   = 4 * 20 * 10 * 10 * 28;  // 224,000
static constexpr int W1SN  = 2 * 4 * 20 * 4 * 128 * 32; // 2,621,440 ushorts
static constexpr int XBT   = 24 * 4 * 512 * 32;      // per-parity xb elems

using bf16x8 = __attribute__((ext_vector_type(8))) short;  // 4 VGPRs
using f32x4  = __attribute__((ext_vector_type(4))) float;

__device__ __forceinline__ unsigned short f2bf(float f) {  // RNE float->bf16
  unsigned u = __float_as_uint(f);
  u += 0x7fff + ((u >> 16) & 1);
  return (unsigned short)(u >> 16);
}
__device__ __forceinline__ float bf2f(unsigned short h) {
  return __uint_as_float((unsigned)h << 16);
}

__device__ __forceinline__ void gload16(const void* g, void* l) {
  __builtin_amdgcn_global_load_lds(
      (const __attribute__((address_space(1))) unsigned int*)g,
      (__attribute__((address_space(3))) unsigned int*)l, 16, 0, 0);
}

// -- kernel 1: x[b][ix][y][t] -> xb{E,O}_{hi,lo}[p][y][ks][b][kk] (k-sliced) --
__global__ __launch_bounds__(256) void k_xbt(const float* __restrict__ x,
                                             unsigned short* __restrict__ xbh,
                                             unsigned short* __restrict__ xbl) {
  __shared__ float lds[64][241];
  const int ix = blockIdx.x;               // 0..23
  const int b0 = blockIdx.y * 64;
  const int tid = threadIdx.x;
  const int p = ix & 1;                    // parity table
  const int c0 = (ix >> 1) * 10;           // column base within table
  #pragma unroll 4
  for (int i = 0; i < 60; ++i) {
    int idx = i * 256 + tid;
    int yt = idx % 240, lb = idx / 240;    // contiguous reads
    lds[lb][yt] = x[(size_t)(b0 + lb) * 5760 + ix * 240 + yt];
  }
  __syncthreads();
  #pragma unroll
  for (int i = 0; i < 6; ++i) {
    int q = i * 256 + tid;
    int lb = q & 63, y = q >> 6;           // y in [0,24)
    const int b = b0 + lb;
    const float* src = &lds[lb][y * 10];
    #pragma unroll
    for (int k0 = 0; k0 < 10; ++k0) {
      const int k = c0 + k0;
      const int ks = k >> 5, kk = k & 31;
      const size_t a = (size_t)p * XBT +
                       (((size_t)(y * 4 + ks) * 512 + b) * 32 + kk);
      float f = src[k0];
      unsigned short hh = f2bf(f);
      xbh[a] = hh;
      xbl[a] = f2bf(f - bf2f(hh));
    }
    if (ix < 2) {                          // zero tail cols 120..127 (k-pad)
      #pragma unroll
      for (int k = 120; k < 128; ++k) {
        const size_t a = (size_t)p * XBT +
                         (((size_t)(y * 4 + 3) * 512 + b) * 32 + (k & 31));
        xbh[a] = 0; xbl[a] = 0;
      }
    }
  }
}

// --- kernel 2: tp-major slot tables. rowb2[(typ*10+tp)*24+ey] = exclusive
// slot base within typ; tpbm[..] = 24-bit ex activity mask. cellmeta[slot]=ex,
// mval[slot]=mask value, slots ordered (typ, tp, ey, ex).
__global__ __launch_bounds__(256) void k_meta(const float* __restrict__ mask,
                                              int* __restrict__ rowb2,
                                              int* __restrict__ tpbm,
                                              int* __restrict__ basep,
                                              int* __restrict__ cellmeta,
                                              float* __restrict__ mval) {
  __shared__ int tot[4];
  __shared__ int sb[4];
  const int typ = threadIdx.x >> 6, lane = threadIdx.x & 63;  // 1 wave/typ
  int running = 0;
  for (int tp = 0; tp < 10; ++tp)
    for (int ey = 0; ey < 24; ++ey) {
      int act = 0;
      if (lane < 24)
        act = (mask[typ * 5760 + tp * 576 + ey * 24 + lane] != 0.0f) ? 1 : 0;
      const unsigned long long bl = __ballot(act);
      const int m = (int)(bl & 0xFFFFFFull);
      if (lane == 0) {
        rowb2[(typ * 10 + tp) * 24 + ey] = running;
        tpbm[(typ * 10 + tp) * 24 + ey] = m;
      }
      running += __popc(m);
    }
  if (lane == 0) tot[typ] = running;
  __syncthreads();
  if (threadIdx.x == 0) {
    int a = 0;
    for (int q = 0; q < 4; ++q) { basep[q] = a; sb[q] = a; a += tot[q]; }
  }
  __syncthreads();
  for (int tp = 0; tp < 10; ++tp)
    for (int ey = 0; ey < 24; ++ey) {
      const int ii = (typ * 10 + tp) * 24 + ey;
      const int m = tpbm[ii];
      const int base = sb[typ] + rowb2[ii];
      if (lane < 24 && ((m >> lane) & 1)) {
        const int idx = base + __popc(m & ((1 << lane) - 1));
        cellmeta[idx] = lane;                       // ex
        mval[idx] = mask[typ * 5760 + tp * 576 + ey * 24 + lane];
      }
    }
}

// ---- kernel 2b: wz[typ][ky][tp][ot][c] zero-padded conv2 weights ----
__global__ __launch_bounds__(256) void k_wz(const float* __restrict__ w2,
                                            float* __restrict__ wz) {
  int idx = blockIdx.x * 256 + threadIdx.x;
  if (idx >= WZN) return;
  int c = idx % 28; int r = idx / 28;
  int ot = r % 10; r /= 10;
  int tp = r % 10; r /= 10;
  int ky = r % 20; int typ = r / 20;
  int kt = tp - ot + 7;
  float v = 0.0f;
  if (kt >= 0 && kt < 10 && c >= 3 && c <= 22)
    v = w2[typ * 4000 + kt * 400 + ky * 20 + (c - 3)];
  wz[idx] = v;
}

// -- kernel 2c: w1s_{hi,lo}[h][typ][ky][ks][r][kk] k-sliced im2col tables --
// h=0: ox odd, xx even; h=1: ox even, xx odd. r=(ox>>1)*10+ot, k=(xx>>1)*10+t
__global__ __launch_bounds__(256) void k_w1m(const float* __restrict__ w1,
                                             unsigned short* __restrict__ w1mh,
                                             unsigned short* __restrict__ w1ml) {
  int idx = blockIdx.x * 256 + threadIdx.x;
  if (idx >= W1SN) return;
  int kk = idx & 31;
  int r = (idx >> 5) & 127;
  int rest = idx >> 12;
  int ks = rest & 3; rest >>= 2;
  int ky = rest % 20; rest /= 20;
  int typ = rest % 4; int h = rest / 4;
  int c = ks * 32 + kk;
  float v = 0.0f;
  if (r < 120 && c < 120) {
    int ox = 2 * (r / 10) + (h == 0 ? 1 : 0);
    int ot = r % 10;
    int xx = 2 * (c / 10) + (h == 0 ? 0 : 1);
    int t  = c % 10;
    int sx = xx - ox + 19;                 // even by parity construction
    int kt = t - ot + 7;
    if (sx >= 0 && sx <= 38 && (unsigned)kt <= 9u)
      v = w1[typ * 4000 + kt * 400 + ky * 20 + (sx >> 1)];
  }
  unsigned short h16 = f2bf(v);
  w1mh[idx] = h16;
  w1ml[idx] = f2bf(v - bf2f(h16));
}

// -- kernel 3: conv1 MFMA, m97-style staging; r31 3-product split; r32
// epilogue renumbered via rowb2/tpbm (tp-major slots).
__global__ __launch_bounds__(256) void k_conv1m(
    const unsigned short* __restrict__ xbh,   // [2][24][4][512][32]
    const unsigned short* __restrict__ xbl,
    const unsigned short* __restrict__ w1mh,  // [2][4][20][4][128][32]
    const unsigned short* __restrict__ w1ml,
    const int* __restrict__ rowb2, const int* __restrict__ tpbm,
    const int* __restrict__ basep, const float* __restrict__ mval,
    float* __restrict__ h1c) {
  __shared__ unsigned short lds[2][12288];   // 2 x 24 KiB
  const int lin = blockIdx.x;                // 0..1535
  const int cx = lin & 7;                    // XCD (round-robin assumed)
  const int typ = cx >> 1, half = cx & 1;
  const int i = lin >> 3;                    // 0..191
  const int n0 = (i & 7) * 64;               // n-strip innermost
  const int rest = i >> 3;                   // 0..23
  const int h = rest & 1;                    // parity half: 0=odd-ox, 1=even
  const int oy = half * 12 + (rest >> 1);
  const int w = threadIdx.x >> 6;            // wave 0..3 -> M tiles w*2,w*2+1
  const int lane = threadIdx.x & 63;
  const int l15 = lane & 15;
  const int kg = (lane >> 4) * 8;            // k sub-offset within 32

  // valid same-parity yy range: sy = yy-oy+19 in [0,38]
  const int py = (oy + 1) & 1;
  int ylo = oy - 19; if (ylo < 0) ylo = 0;
  ylo += (ylo & 1) ^ py;
  int yhi = oy + 19; if (yhi > 23) yhi = 23;
  yhi -= (yhi & 1) ^ py;
  const int ns = (((yhi - ylo) >> 1) + 1) * 4;   // 4 k-slices per yy

  f32x4 acc[2][4];
  #pragma unroll
  for (int mi = 0; mi < 2; ++mi)
    #pragma unroll
    for (int nt = 0; nt < 4; ++nt) {
      f32x4 z = {0.f, 0.f, 0.f, 0.f};
      acc[mi][nt] = z;
    }

  auto stage = [&](int s, int bufi) {
    const int yy = ylo + ((s >> 2) << 1);
    const int ks = s & 3;
    const int ky = (yy - oy + 19) >> 1;
    const size_t asl = ((size_t)((h * 4 + typ) * 20 + ky) * 4 + ks) << 12;
    const unsigned short* Ah = w1mh + asl;
    const unsigned short* Al = w1ml + asl;
    const size_t bsl = (((size_t)(h * 24 + yy) * 4 + ks) << 14) +
                       (size_t)n0 * 32;
    const unsigned short* Bh = xbh + bsl;
    const unsigned short* Bl = xbl + bsl;
    char* lb = (char*)&lds[bufi][0];
    #pragma unroll
    for (int ia = 0; ia < 2; ++ia) {          // A: 8192 B per table
      const int L = ia * 4096 + w * 1024 + lane * 16;
      const int row = L >> 6;
      const int g = row * 64 + ((((L >> 4) & 3) ^ ((row >> 1) & 3)) << 4);
      gload16((const char*)Ah + g, lb + ia * 4096 + w * 1024);
      gload16((const char*)Al + g, lb + 8192 + ia * 4096 + w * 1024);
    }
    {                                          // B: 4096 B per table
      const int L = w * 1024 + lane * 16;
      const int row = L >> 6;
      const int g = row * 64 + ((((L >> 4) & 3) ^ ((row >> 1) & 3)) << 4);
      gload16((const char*)Bh + g, lb + 16384 + w * 1024);
      gload16((const char*)Bl + g, lb + 20480 + w * 1024);
    }
  };

  stage(0, 0);
  __syncthreads();
  int cur = 0;
  for (int s = 0; s < ns; ++s) {
    if (s + 1 < ns) stage(s + 1, cur ^ 1);     // issue next-slice loads first
    const unsigned short* bufb = &lds[cur][0];
    bf16x8 bhv[4], blv[4];
    #pragma unroll
    for (int nt = 0; nt < 4; ++nt) {
      const int n = nt * 16 + l15;
      const int by = n * 64 + (((kg >> 3) ^ ((n >> 1) & 3)) << 4);
      bhv[nt] = *(const bf16x8*)((const char*)(bufb + 8192) + by);
      blv[nt] = *(const bf16x8*)((const char*)(bufb + 10240) + by);
    }
    #pragma unroll
    for (int mi = 0; mi < 2; ++mi) {
      const int r = (w * 2 + mi) * 16 + l15;
      const int ay = r * 64 + (((kg >> 3) ^ ((r >> 1) & 3)) << 4);
      const bf16x8 ah = *(const bf16x8*)((const char*)bufb + ay);
      const bf16x8 al = *(const bf16x8*)((const char*)(bufb + 4096) + ay);
      #pragma unroll
      for (int nt = 0; nt < 4; ++nt) {
        acc[mi][nt] = __builtin_amdgcn_mfma_f32_16x16x32_bf16(
            ah, blv[nt], acc[mi][nt], 0, 0, 0);
        acc[mi][nt] = __builtin_amdgcn_mfma_f32_16x16x32_bf16(
            al, bhv[nt], acc[mi][nt], 0, 0, 0);
        acc[mi][nt] = __builtin_amdgcn_mfma_f32_16x16x32_bf16(
            ah, bhv[nt], acc[mi][nt], 0, 0, 0);
      }
    }
    __syncthreads();                           // drain staging + ds reads
    cur ^= 1;
  }

  // epilogue: compact write with fused relu * mval -> h1c (tp-major slots)
  const int bo = basep[typ];
  #pragma unroll
  for (int mi = 0; mi < 2; ++mi) {
    #pragma unroll
    for (int reg = 0; reg < 4; ++reg) {
      const int r = (w * 2 + mi) * 16 + (lane >> 4) * 4 + reg;
      if (r >= 120) continue;                  // padded rows
      const int ox = 2 * (r / 10) + (h == 0 ? 1 : 0);
      const int ot = r % 10;
      const int ii = (typ * 10 + ot) * 24 + oy;
      const int bm = tpbm[ii];
      if ((bm >> ox) & 1) {
        const int slot = bo + rowb2[ii] + __popc(bm & ((1 << ox) - 1));
        const float mv = mval[slot];
        #pragma unroll
        for (int nt = 0; nt < 4; ++nt)
          h1c[(size_t)slot * 512 + n0 + nt * 16 + l15] =
              fmaxf(acc[mi][nt][reg], 0.0f) * mv;
      }
    }
  }
}

// -- kernel 4: conv2 (r32). Unrolled tp loop -> compile-time ot bounds
// (27.6 avg FMAs/slot, -31%); run bounds from rowb2/tpbm scalar popc;
// weights as SGPR operands; depth-2 slot pipeline. Grid/outputs = r26.
__global__ __launch_bounds__(256) void k_conv2(const float* __restrict__ h1c,
                                               const float* __restrict__ wz,
                                               const int* __restrict__ rowb2,
                                               const int* __restrict__ tpbm,
                                               const int* __restrict__ basep,
                                               const int* __restrict__ cellmeta,
                                               float* __restrict__ part) {
  const int lin = blockIdx.x;
  const int cx = lin & 7, i = lin >> 3;
  const int typ = cx >> 1;
  const int oy  = (cx & 1) * 12 + (i % 12);
  const int x12 = i / 12;
  const int tile = x12 >> 1, bh = x12 & 1;
  const int ox0 = tile * 4;
  const int b = bh * 256 + threadIdx.x;
  const int bo = __builtin_amdgcn_readfirstlane(basep[typ]);

  float acc[40];
  #pragma unroll
  for (int i2 = 0; i2 < 40; ++i2) acc[i2] = 0.0f;

  const int ex_lo = ox0 - 10 < 0 ? 0 : ox0 - 10;   // d = ex-ox0+10 in [0,22]
  const int ex_hi = ox0 + 12 > 23 ? 23 : ox0 + 12;
  const int ey0 = oy - 10 < 0 ? 0 : oy - 10;
  const int ey1 = oy + 9 > 23 ? 23 : oy + 9;
  const int mlo = (1 << ex_lo) - 1;
  const int mhi = (ex_hi >= 23) ? 0xFFFFFF : ((1 << (ex_hi + 1)) - 1);

  // fmablock: ex scalar, xv per-lane; olo/ohi fold to constants after the
  // tp-unroll -> straight-line FMAs with SGPR weight operands.
  auto fb = [&](int ex, float xv, int rb2, int olo, int ohi) {
    const float* wrow = wz + rb2 + ex;
    #pragma unroll
    for (int ot = 0; ot < 10; ++ot)
      if (ot >= olo && ot <= ohi) {
        #pragma unroll
        for (int j = 0; j < 4; ++j)
          acc[ot * 4 + j] = fmaf(wrow[ot * 28 + 3 - j], xv, acc[ot * 4 + j]);
      }
  };

  for (int ey = ey0; ey <= ey1; ++ey) {
    const int ky = ey - oy + 10;
    const int rbase = (typ * 20 + ky) * 2800 + 10 - ox0;
    #pragma unroll
    for (int tp = 0; tp < 10; ++tp) {
      const int olo = tp < 2 ? 0 : tp - 2;       // compile-time after unroll
      const int ohi = tp > 2 ? 9 : tp + 7;
      const int ii = (typ * 10 + tp) * 24 + ey;
      const int bm = __builtin_amdgcn_readfirstlane(tpbm[ii]);
      const int rb = __builtin_amdgcn_readfirstlane(rowb2[ii]);
      const int s_lo = bo + rb + __popc(bm & mlo);
      const int s_hi = bo + rb + __popc(bm & mhi);
      const int rb2 = rbase + tp * 280;
      int s = s_lo;
      for (; s + 2 <= s_hi; s += 2) {            // depth-2: hoist ex+xv
        const int e0 = __builtin_amdgcn_readfirstlane(cellmeta[s]);
        const int e1 = __builtin_amdgcn_readfirstlane(cellmeta[s + 1]);
        const float xv0 = h1c[(size_t)s * 512 + b];
        const float xv1 = h1c[(size_t)(s + 1) * 512 + b];
        fb(e0, xv0, rb2, olo, ohi);
        fb(e1, xv1, rb2, olo, ohi);
      }
      if (s < s_hi) {                            // tail
        const int e0 = __builtin_amdgcn_readfirstlane(cellmeta[s]);
        const float xv0 = h1c[(size_t)s * 512 + b];
        fb(e0, xv0, rb2, olo, ohi);
      }
    }
  }
  #pragma unroll
  for (int ot = 0; ot < 10; ++ot)
    #pragma unroll
    for (int j = 0; j < 4; ++j)
      part[(size_t)(((typ * 10 + ot) * 24 + oy) * 24 + ox0 + j) * 512 + b] =
          acc[ot * 4 + j];
}

// ------ kernel 5: sum 4 typ-partials + transpose to out[b][x][y][t] ------
__global__ __launch_bounds__(256) void k_reduce(const float* __restrict__ part,
                                                float* __restrict__ out) {
  __shared__ float lds[64][241];
  const int xb = blockIdx.x;
  const int b0 = blockIdx.y * 64;
  const int tid = threadIdx.x;
  #pragma unroll 4
  for (int i = 0; i < 60; ++i) {
    int idx = i * 256 + tid;
    int yt = idx >> 6, lb = idx & 63;
    int y = yt / 10, t = yt % 10;
    size_t a = (size_t)((t * 24 + y) * 24 + xb) * 512 + b0 + lb;
    lds[lb][yt] = part[a] + part[a + P] + part[a + 2 * (size_t)P] +
                  part[a + 3 * (size_t)P];
  }
  __syncthreads();
  #pragma unroll 4
  for (int i = 0; i < 60; ++i) {
    int idx = i * 256 + tid;
    int yt = idx % 240, lb = idx / 240;
    out[(size_t)(b0 + lb) * 5760 + xb * 240 + yt] = lds[lb][yt];
  }
}

extern "C" void kernel_launch(void* const* d_in, const int* in_sizes, int n_in,
                              void* d_out, int out_size, void* d_ws, size_t ws_size,
                              hipStream_t stream) {
  const float* x    = (const float*)d_in[0];
  const float* w1   = (const float*)d_in[1];
  const float* w2   = (const float*)d_in[2];
  const float* mask = (const float*)d_in[3];
  float* out = (float*)d_out;
  float* wsf = (float*)d_ws;

  int* rowb2    = (int*)d_ws;                            // 960
  int* tpbm     = rowb2 + 960;                           // 960
  int* basep    = rowb2 + 4608;
  int* cellmeta = rowb2 + 5120;                          // 5760
  float* mval   = wsf + 14336;
  float* part = wsf + FBASE;                             // conv2 out
  unsigned short* xbh  = (unsigned short*)(wsf + FBASE);               // conv1
  unsigned short* xbl  = (unsigned short*)(wsf + FBASE + 1572864);     // conv1
  unsigned short* w1mh = (unsigned short*)(wsf + FBASE + 3145728);     // conv1
  unsigned short* w1ml = (unsigned short*)(wsf + FBASE + 4456448);     // conv1
  float* h1c = wsf + FBASE + (size_t)4 * P;
  float* wz  = wsf + FBASE + (size_t)5 * P;

  k_meta<<<1, 256, 0, stream>>>(mask, rowb2, tpbm, basep, cellmeta, mval);
  k_wz<<<(WZN + 255) / 256, 256, 0, stream>>>(w2, wz);
  k_w1m<<<(W1SN + 255) / 256, 256, 0, stream>>>(w1, w1mh, w1ml);
  k_xbt<<<dim3(24, 8), 256, 0, stream>>>(x, xbh, xbl);
  k_conv1m<<<1536, 256, 0, stream>>>(xbh, xbl, w1mh, w1ml,
                                     rowb2, tpbm, basep, mval, h1c);
  k_conv2<<<1152, 256, 0, stream>>>(h1c, wz, rowb2, tpbm, basep,
                                    cellmeta, part);
  k_reduce<<<dim3(24, 8), 256, 0, stream>>>(part, out);
}

// Round 12
// 389.549 us; speedup vs baseline: 1.2608x; 1.2608x over previous
//
#include <hip/hip_runtime.h>

// PinkNet: x(512,24,24,10,1) -T-> (B,1,T,Y,X) -conv1(dil 2,2)-> relu -> *mask
//          -conv2-> -T-> out.
// r33: = r32 (tp-major slots; conv2 compile-time kt-skip, 274->236us
//      MEASURED) but k_meta re-parallelized. r32's k_meta was 2x240 serial
//      ballot rounds (~100us, the total regression 422->491). New k_meta:
//      phase A: 960 row-masks in parallel (thread/row, 24 indep loads;
//      mask base = row*24 exactly); phase B: per-typ exclusive scan by 4
//      threads over LDS counts; phase C: rowb2 + cellmeta/mval fills,
//      thread/row. Outputs bit-identical to r32's k_meta.
//      conv1m = r31 (3-product split) + r32 epilogue. Others unchanged.
//
// ws ints @0: rowb2[960], tpbm[960]@960, basep[4]@4608, cellmeta[5760]@5120
// floats: mval[5760] @14336 ; FBASE=20480:
//   [FBASE..FBASE+4P)  part (conv2 out). conv1-only aliases (5.77M < 4P):
//     xbh @+0 (1572864 fl), xbl @+1572864, w1mh @+3145728 (1310720 fl),
//     w1ml @+4456448
//   [FBASE+4P..FBASE+5P) h1c[5760][512] fp32
//   [FBASE+5P..]         wz[224000]

#define NSLOT 5760
static constexpr int P     = 10 * 24 * 24 * 512;     // 2,949,120 = NSLOT*512
static constexpr int FBASE = 20480;
static constexpr int WZN   = 4 * 20 * 10 * 10 * 28;  // 224,000
static constexpr int W1SN  = 2 * 4 * 20 * 4 * 128 * 32; // 2,621,440 ushorts
static constexpr int XBT   = 24 * 4 * 512 * 32;      // per-parity xb elems

using bf16x8 = __attribute__((ext_vector_type(8))) short;  // 4 VGPRs
using f32x4  = __attribute__((ext_vector_type(4))) float;

__device__ __forceinline__ unsigned short f2bf(float f) {  // RNE float->bf16
  unsigned u = __float_as_uint(f);
  u += 0x7fff + ((u >> 16) & 1);
  return (unsigned short)(u >> 16);
}
__device__ __forceinline__ float bf2f(unsigned short h) {
  return __uint_as_float((unsigned)h << 16);
}

__device__ __forceinline__ void gload16(const void* g, void* l) {
  __builtin_amdgcn_global_load_lds(
      (const __attribute__((address_space(1))) unsigned int*)g,
      (__attribute__((address_space(3))) unsigned int*)l, 16, 0, 0);
}

// -- kernel 1: x[b][ix][y][t] -> xb{E,O}_{hi,lo}[p][y][ks][b][kk] (k-sliced) --
__global__ __launch_bounds__(256) void k_xbt(const float* __restrict__ x,
                                             unsigned short* __restrict__ xbh,
                                             unsigned short* __restrict__ xbl) {
  __shared__ float lds[64][241];
  const int ix = blockIdx.x;               // 0..23
  const int b0 = blockIdx.y * 64;
  const int tid = threadIdx.x;
  const int p = ix & 1;                    // parity table
  const int c0 = (ix >> 1) * 10;           // column base within table
  #pragma unroll 4
  for (int i = 0; i < 60; ++i) {
    int idx = i * 256 + tid;
    int yt = idx % 240, lb = idx / 240;    // contiguous reads
    lds[lb][yt] = x[(size_t)(b0 + lb) * 5760 + ix * 240 + yt];
  }
  __syncthreads();
  #pragma unroll
  for (int i = 0; i < 6; ++i) {
    int q = i * 256 + tid;
    int lb = q & 63, y = q >> 6;           // y in [0,24)
    const int b = b0 + lb;
    const float* src = &lds[lb][y * 10];
    #pragma unroll
    for (int k0 = 0; k0 < 10; ++k0) {
      const int k = c0 + k0;
      const int ks = k >> 5, kk = k & 31;
      const size_t a = (size_t)p * XBT +
                       (((size_t)(y * 4 + ks) * 512 + b) * 32 + kk);
      float f = src[k0];
      unsigned short hh = f2bf(f);
      xbh[a] = hh;
      xbl[a] = f2bf(f - bf2f(hh));
    }
    if (ix < 2) {                          // zero tail cols 120..127 (k-pad)
      #pragma unroll
      for (int k = 120; k < 128; ++k) {
        const size_t a = (size_t)p * XBT +
                         (((size_t)(y * 4 + 3) * 512 + b) * 32 + (k & 31));
        xbh[a] = 0; xbl[a] = 0;
      }
    }
  }
}

// --- kernel 2: tp-major slot tables (r33: parallel build). Outputs match
// r32: rowb2[(typ*10+tp)*24+ey] = exclusive base within typ (tp,ey order);
// tpbm = 24-bit ex mask; cellmeta[slot] = ex; mval[slot] = mask value.
__global__ __launch_bounds__(256) void k_meta(const float* __restrict__ mask,
                                              int* __restrict__ rowb2,
                                              int* __restrict__ tpbm,
                                              int* __restrict__ basep,
                                              int* __restrict__ cellmeta,
                                              float* __restrict__ mval) {
  __shared__ int cnt[960];
  __shared__ int pref[960];
  __shared__ int sb[4];
  const int tid = threadIdx.x;
  // Phase A: one thread per row (typ*240 + tp*24 + ey); mask base = row*24.
  for (int r = tid; r < 960; r += 256) {
    const float* mrow = mask + r * 24;
    int m = 0;
    #pragma unroll
    for (int e = 0; e < 24; ++e)
      if (mrow[e] != 0.0f) m |= (1 << e);
    tpbm[r] = m;
    cnt[r] = __popc(m);
  }
  __syncthreads();
  // Phase B: exclusive scan over 240 rows per typ (4 threads, LDS).
  if (tid < 4) {
    int run = 0;
    #pragma unroll 8
    for (int j = 0; j < 240; ++j) {
      pref[tid * 240 + j] = run;
      run += cnt[tid * 240 + j];
    }
    cnt[tid] = run;                          // reuse cnt[0..3] = totals
  }
  __syncthreads();
  if (tid == 0) {
    int a = 0;
    for (int q = 0; q < 4; ++q) { basep[q] = a; sb[q] = a; a += cnt[q]; }
  }
  __syncthreads();
  // Phase C: rowb2 + compact cellmeta/mval fills (thread per row).
  for (int r = tid; r < 960; r += 256) {
    rowb2[r] = pref[r];
    const int m = tpbm[r];
    int idx = sb[r / 240] + pref[r];
    const float* mrow = mask + r * 24;
    for (int e = 0; e < 24; ++e)
      if ((m >> e) & 1) {
        cellmeta[idx] = e;
        mval[idx] = mrow[e];
        ++idx;
      }
  }
}

// ---- kernel 2b: wz[typ][ky][tp][ot][c] zero-padded conv2 weights ----
__global__ __launch_bounds__(256) void k_wz(const float* __restrict__ w2,
                                            float* __restrict__ wz) {
  int idx = blockIdx.x * 256 + threadIdx.x;
  if (idx >= WZN) return;
  int c = idx % 28; int r = idx / 28;
  int ot = r % 10; r /= 10;
  int tp = r % 10; r /= 10;
  int ky = r % 20; int typ = r / 20;
  int kt = tp - ot + 7;
  float v = 0.0f;
  if (kt >= 0 && kt < 10 && c >= 3 && c <= 22)
    v = w2[typ * 4000 + kt * 400 + ky * 20 + (c - 3)];
  wz[idx] = v;
}

// -- kernel 2c: w1s_{hi,lo}[h][typ][ky][ks][r][kk] k-sliced im2col tables --
// h=0: ox odd, xx even; h=1: ox even, xx odd. r=(ox>>1)*10+ot, k=(xx>>1)*10+t
__global__ __launch_bounds__(256) void k_w1m(const float* __restrict__ w1,
                                             unsigned short* __restrict__ w1mh,
                                             unsigned short* __restrict__ w1ml) {
  int idx = blockIdx.x * 256 + threadIdx.x;
  if (idx >= W1SN) return;
  int kk = idx & 31;
  int r = (idx >> 5) & 127;
  int rest = idx >> 12;
  int ks = rest & 3; rest >>= 2;
  int ky = rest % 20; rest /= 20;
  int typ = rest % 4; int h = rest / 4;
  int c = ks * 32 + kk;
  float v = 0.0f;
  if (r < 120 && c < 120) {
    int ox = 2 * (r / 10) + (h == 0 ? 1 : 0);
    int ot = r % 10;
    int xx = 2 * (c / 10) + (h == 0 ? 0 : 1);
    int t  = c % 10;
    int sx = xx - ox + 19;                 // even by parity construction
    int kt = t - ot + 7;
    if (sx >= 0 && sx <= 38 && (unsigned)kt <= 9u)
      v = w1[typ * 4000 + kt * 400 + ky * 20 + (sx >> 1)];
  }
  unsigned short h16 = f2bf(v);
  w1mh[idx] = h16;
  w1ml[idx] = f2bf(v - bf2f(h16));
}

// -- kernel 3: conv1 MFMA, m97-style staging; r31 3-product split; r32
// epilogue renumbered via rowb2/tpbm (tp-major slots).
__global__ __launch_bounds__(256) void k_conv1m(
    const unsigned short* __restrict__ xbh,   // [2][24][4][512][32]
    const unsigned short* __restrict__ xbl,
    const unsigned short* __restrict__ w1mh,  // [2][4][20][4][128][32]
    const unsigned short* __restrict__ w1ml,
    const int* __restrict__ rowb2, const int* __restrict__ tpbm,
    const int* __restrict__ basep, const float* __restrict__ mval,
    float* __restrict__ h1c) {
  __shared__ unsigned short lds[2][12288];   // 2 x 24 KiB
  const int lin = blockIdx.x;                // 0..1535
  const int cx = lin & 7;                    // XCD (round-robin assumed)
  const int typ = cx >> 1, half = cx & 1;
  const int i = lin >> 3;                    // 0..191
  const int n0 = (i & 7) * 64;               // n-strip innermost
  const int rest = i >> 3;                   // 0..23
  const int h = rest & 1;                    // parity half: 0=odd-ox, 1=even
  const int oy = half * 12 + (rest >> 1);
  const int w = threadIdx.x >> 6;            // wave 0..3 -> M tiles w*2,w*2+1
  const int lane = threadIdx.x & 63;
  const int l15 = lane & 15;
  const int kg = (lane >> 4) * 8;            // k sub-offset within 32

  // valid same-parity yy range: sy = yy-oy+19 in [0,38]
  const int py = (oy + 1) & 1;
  int ylo = oy - 19; if (ylo < 0) ylo = 0;
  ylo += (ylo & 1) ^ py;
  int yhi = oy + 19; if (yhi > 23) yhi = 23;
  yhi -= (yhi & 1) ^ py;
  const int ns = (((yhi - ylo) >> 1) + 1) * 4;   // 4 k-slices per yy

  f32x4 acc[2][4];
  #pragma unroll
  for (int mi = 0; mi < 2; ++mi)
    #pragma unroll
    for (int nt = 0; nt < 4; ++nt) {
      f32x4 z = {0.f, 0.f, 0.f, 0.f};
      acc[mi][nt] = z;
    }

  auto stage = [&](int s, int bufi) {
    const int yy = ylo + ((s >> 2) << 1);
    const int ks = s & 3;
    const int ky = (yy - oy + 19) >> 1;
    const size_t asl = ((size_t)((h * 4 + typ) * 20 + ky) * 4 + ks) << 12;
    const unsigned short* Ah = w1mh + asl;
    const unsigned short* Al = w1ml + asl;
    const size_t bsl = (((size_t)(h * 24 + yy) * 4 + ks) << 14) +
                       (size_t)n0 * 32;
    const unsigned short* Bh = xbh + bsl;
    const unsigned short* Bl = xbl + bsl;
    char* lb = (char*)&lds[bufi][0];
    #pragma unroll
    for (int ia = 0; ia < 2; ++ia) {          // A: 8192 B per table
      const int L = ia * 4096 + w * 1024 + lane * 16;
      const int row = L >> 6;
      const int g = row * 64 + ((((L >> 4) & 3) ^ ((row >> 1) & 3)) << 4);
      gload16((const char*)Ah + g, lb + ia * 4096 + w * 1024);
      gload16((const char*)Al + g, lb + 8192 + ia * 4096 + w * 1024);
    }
    {                                          // B: 4096 B per table
      const int L = w * 1024 + lane * 16;
      const int row = L >> 6;
      const int g = row * 64 + ((((L >> 4) & 3) ^ ((row >> 1) & 3)) << 4);
      gload16((const char*)Bh + g, lb + 16384 + w * 1024);
      gload16((const char*)Bl + g, lb + 20480 + w * 1024);
    }
  };

  stage(0, 0);
  __syncthreads();
  int cur = 0;
  for (int s = 0; s < ns; ++s) {
    if (s + 1 < ns) stage(s + 1, cur ^ 1);     // issue next-slice loads first
    const unsigned short* bufb = &lds[cur][0];
    bf16x8 bhv[4], blv[4];
    #pragma unroll
    for (int nt = 0; nt < 4; ++nt) {
      const int n = nt * 16 + l15;
      const int by = n * 64 + (((kg >> 3) ^ ((n >> 1) & 3)) << 4);
      bhv[nt] = *(const bf16x8*)((const char*)(bufb + 8192) + by);
      blv[nt] = *(const bf16x8*)((const char*)(bufb + 10240) + by);
    }
    #pragma unroll
    for (int mi = 0; mi < 2; ++mi) {
      const int r = (w * 2 + mi) * 16 + l15;
      const int ay = r * 64 + (((kg >> 3) ^ ((r >> 1) & 3)) << 4);
      const bf16x8 ah = *(const bf16x8*)((const char*)bufb + ay);
      const bf16x8 al = *(const bf16x8*)((const char*)(bufb + 4096) + ay);
      #pragma unroll
      for (int nt = 0; nt < 4; ++nt) {
        acc[mi][nt] = __builtin_amdgcn_mfma_f32_16x16x32_bf16(
            ah, blv[nt], acc[mi][nt], 0, 0, 0);
        acc[mi][nt] = __builtin_amdgcn_mfma_f32_16x16x32_bf16(
            al, bhv[nt], acc[mi][nt], 0, 0, 0);
        acc[mi][nt] = __builtin_amdgcn_mfma_f32_16x16x32_bf16(
            ah, bhv[nt], acc[mi][nt], 0, 0, 0);
      }
    }
    __syncthreads();                           // drain staging + ds reads
    cur ^= 1;
  }

  // epilogue: compact write with fused relu * mval -> h1c (tp-major slots)
  const int bo = basep[typ];
  #pragma unroll
  for (int mi = 0; mi < 2; ++mi) {
    #pragma unroll
    for (int reg = 0; reg < 4; ++reg) {
      const int r = (w * 2 + mi) * 16 + (lane >> 4) * 4 + reg;
      if (r >= 120) continue;                  // padded rows
      const int ox = 2 * (r / 10) + (h == 0 ? 1 : 0);
      const int ot = r % 10;
      const int ii = (typ * 10 + ot) * 24 + oy;
      const int bm = tpbm[ii];
      if ((bm >> ox) & 1) {
        const int slot = bo + rowb2[ii] + __popc(bm & ((1 << ox) - 1));
        const float mv = mval[slot];
        #pragma unroll
        for (int nt = 0; nt < 4; ++nt)
          h1c[(size_t)slot * 512 + n0 + nt * 16 + l15] =
              fmaxf(acc[mi][nt][reg], 0.0f) * mv;
      }
    }
  }
}

// -- kernel 4: conv2 (r32, unchanged — measured 236us). Unrolled tp loop ->
// compile-time ot bounds (27.6 avg FMAs/slot); run bounds from rowb2/tpbm
// scalar popc; weights as SGPR operands; depth-2 slot pipeline.
__global__ __launch_bounds__(256) void k_conv2(const float* __restrict__ h1c,
                                               const float* __restrict__ wz,
                                               const int* __restrict__ rowb2,
                                               const int* __restrict__ tpbm,
                                               const int* __restrict__ basep,
                                               const int* __restrict__ cellmeta,
                                               float* __restrict__ part) {
  const int lin = blockIdx.x;
  const int cx = lin & 7, i = lin >> 3;
  const int typ = cx >> 1;
  const int oy  = (cx & 1) * 12 + (i % 12);
  const int x12 = i / 12;
  const int tile = x12 >> 1, bh = x12 & 1;
  const int ox0 = tile * 4;
  const int b = bh * 256 + threadIdx.x;
  const int bo = __builtin_amdgcn_readfirstlane(basep[typ]);

  float acc[40];
  #pragma unroll
  for (int i2 = 0; i2 < 40; ++i2) acc[i2] = 0.0f;

  const int ex_lo = ox0 - 10 < 0 ? 0 : ox0 - 10;   // d = ex-ox0+10 in [0,22]
  const int ex_hi = ox0 + 12 > 23 ? 23 : ox0 + 12;
  const int ey0 = oy - 10 < 0 ? 0 : oy - 10;
  const int ey1 = oy + 9 > 23 ? 23 : oy + 9;
  const int mlo = (1 << ex_lo) - 1;
  const int mhi = (ex_hi >= 23) ? 0xFFFFFF : ((1 << (ex_hi + 1)) - 1);

  auto fb = [&](int ex, float xv, int rb2, int olo, int ohi) {
    const float* wrow = wz + rb2 + ex;
    #pragma unroll
    for (int ot = 0; ot < 10; ++ot)
      if (ot >= olo && ot <= ohi) {
        #pragma unroll
        for (int j = 0; j < 4; ++j)
          acc[ot * 4 + j] = fmaf(wrow[ot * 28 + 3 - j], xv, acc[ot * 4 + j]);
      }
  };

  for (int ey = ey0; ey <= ey1; ++ey) {
    const int ky = ey - oy + 10;
    const int rbase = (typ * 20 + ky) * 2800 + 10 - ox0;
    #pragma unroll
    for (int tp = 0; tp < 10; ++tp) {
      const int olo = tp < 2 ? 0 : tp - 2;       // compile-time after unroll
      const int ohi = tp > 2 ? 9 : tp + 7;
      const int ii = (typ * 10 + tp) * 24 + ey;
      const int bm = __builtin_amdgcn_readfirstlane(tpbm[ii]);
      const int rb = __builtin_amdgcn_readfirstlane(rowb2[ii]);
      const int s_lo = bo + rb + __popc(bm & mlo);
      const int s_hi = bo + rb + __popc(bm & mhi);
      const int rb2 = rbase + tp * 280;
      int s = s_lo;
      for (; s + 2 <= s_hi; s += 2) {            // depth-2: hoist ex+xv
        const int e0 = __builtin_amdgcn_readfirstlane(cellmeta[s]);
        const int e1 = __builtin_amdgcn_readfirstlane(cellmeta[s + 1]);
        const float xv0 = h1c[(size_t)s * 512 + b];
        const float xv1 = h1c[(size_t)(s + 1) * 512 + b];
        fb(e0, xv0, rb2, olo, ohi);
        fb(e1, xv1, rb2, olo, ohi);
      }
      if (s < s_hi) {                            // tail
        const int e0 = __builtin_amdgcn_readfirstlane(cellmeta[s]);
        const float xv0 = h1c[(size_t)s * 512 + b];
        fb(e0, xv0, rb2, olo, ohi);
      }
    }
  }
  #pragma unroll
  for (int ot = 0; ot < 10; ++ot)
    #pragma unroll
    for (int j = 0; j < 4; ++j)
      part[(size_t)(((typ * 10 + ot) * 24 + oy) * 24 + ox0 + j) * 512 + b] =
          acc[ot * 4 + j];
}

// ------ kernel 5: sum 4 typ-partials + transpose to out[b][x][y][t] ------
__global__ __launch_bounds__(256) void k_reduce(const float* __restrict__ part,
                                                float* __restrict__ out) {
  __shared__ float lds[64][241];
  const int xb = blockIdx.x;
  const int b0 = blockIdx.y * 64;
  const int tid = threadIdx.x;
  #pragma unroll 4
  for (int i = 0; i < 60; ++i) {
    int idx = i * 256 + tid;
    int yt = idx >> 6, lb = idx & 63;
    int y = yt / 10, t = yt % 10;
    size_t a = (size_t)((t * 24 + y) * 24 + xb) * 512 + b0 + lb;
    lds[lb][yt] = part[a] + part[a + P] + part[a + 2 * (size_t)P] +
                  part[a + 3 * (size_t)P];
  }
  __syncthreads();
  #pragma unroll 4
  for (int i = 0; i < 60; ++i) {
    int idx = i * 256 + tid;
    int yt = idx % 240, lb = idx / 240;
    out[(size_t)(b0 + lb) * 5760 + xb * 240 + yt] = lds[lb][yt];
  }
}

extern "C" void kernel_launch(void* const* d_in, const int* in_sizes, int n_in,
                              void* d_out, int out_size, void* d_ws, size_t ws_size,
                              hipStream_t stream) {
  const float* x    = (const float*)d_in[0];
  const float* w1   = (const float*)d_in[1];
  const float* w2   = (const float*)d_in[2];
  const float* mask = (const float*)d_in[3];
  float* out = (float*)d_out;
  float* wsf = (float*)d_ws;

  int* rowb2    = (int*)d_ws;                            // 960
  int* tpbm     = rowb2 + 960;                           // 960
  int* basep    = rowb2 + 4608;
  int* cellmeta = rowb2 + 5120;                          // 5760
  float* mval   = wsf + 14336;
  float* part = wsf + FBASE;                             // conv2 out
  unsigned short* xbh  = (unsigned short*)(wsf + FBASE);               // conv1
  unsigned short* xbl  = (unsigned short*)(wsf + FBASE + 1572864);     // conv1
  unsigned short* w1mh = (unsigned short*)(wsf + FBASE + 3145728);     // conv1
  unsigned short* w1ml = (unsigned short*)(wsf + FBASE + 4456448);     // conv1
  float* h1c = wsf + FBASE + (size_t)4 * P;
  float* wz  = wsf + FBASE + (size_t)5 * P;

  k_meta<<<1, 256, 0, stream>>>(mask, rowb2, tpbm, basep, cellmeta, mval);
  k_wz<<<(WZN + 255) / 256, 256, 0, stream>>>(w2, wz);
  k_w1m<<<(W1SN + 255) / 256, 256, 0, stream>>>(w1, w1mh, w1ml);
  k_xbt<<<dim3(24, 8), 256, 0, stream>>>(x, xbh, xbl);
  k_conv1m<<<1536, 256, 0, stream>>>(xbh, xbl, w1mh, w1ml,
                                     rowb2, tpbm, basep, mval, h1c);
  k_conv2<<<1152, 256, 0, stream>>>(h1c, wz, rowb2, tpbm, basep,
                                    cellmeta, part);
  k_reduce<<<dim3(24, 8), 256, 0, stream>>>(part, out);
}